// Round 3
// baseline (290.369 us; speedup 1.0000x reference)
//
#include <hip/hip_runtime.h>
#include <math.h>

#define NH 32
#define NKVH 8
#define GRP 4
#define HD 128
#define LQB 128
#define PTSTRIDE 128
#define KVROW (NKVH * HD)          // 1024 floats per token row
#define QK_SCALE 0.08838834764831845f
#define LOG2E 1.4426950408889634f
#define DEFER_THR 8.0f

typedef __attribute__((ext_vector_type(8))) __bf16 bf16x8;
typedef __attribute__((ext_vector_type(4))) __bf16 bf16x4;
typedef __attribute__((ext_vector_type(4))) float f32x4;

// LDS per buffer: K: 64 keys x 128 d bf16, 256B rows, 16B-chunk XOR swizzle ((key&7)<<4)
//                 Vt: 128 d x 72 keys bf16 (64 + 8 pad -> 144B rows, reads 2-way free)
#define KS_BYTES (64 * 256)
#define VT_STRIDE 144
#define VT_BYTES (128 * VT_STRIDE)
#define KS_OFF(b) ((b) * KS_BYTES)
#define VT_OFF(b) (2 * KS_BYTES + (b) * VT_BYTES)

static __device__ __forceinline__ bf16x8 cvt8s(const float* __restrict__ p, float s) {
    const f32x4 a = *reinterpret_cast<const f32x4*>(p);
    const f32x4 b = *reinterpret_cast<const f32x4*>(p + 4);
    bf16x8 r;
    r[0] = (__bf16)(a[0] * s); r[1] = (__bf16)(a[1] * s);
    r[2] = (__bf16)(a[2] * s); r[3] = (__bf16)(a[3] * s);
    r[4] = (__bf16)(b[0] * s); r[5] = (__bf16)(b[1] * s);
    r[6] = (__bf16)(b[2] * s); r[7] = (__bf16)(b[3] * s);
    return r;
}

// Wave = 16 q-rows of one head; block = 4 heads of one kv group (shared K/V in LDS).
// 64-key steps: 4 independent S^T chains (16 MFMA) + 16 PV MFMA per step.
// Swapped QK^T => softmax lane-local; defer-max (THR=8, log2 domain) skips the
// cross-lane reduce + rescale on almost every step. Double-buffered async staging.
__global__ __launch_bounds__(256, 2)
void attn_fwd(const float* __restrict__ Q,
              const float* __restrict__ Kn,
              const float* __restrict__ Vn,
              const float* __restrict__ Kc,
              const float* __restrict__ Vc,
              const int* __restrict__ PT,
              const int* __restrict__ CTX,
              float* __restrict__ O)
{
    __shared__ __align__(16) unsigned char smem[2 * KS_BYTES + 2 * VT_BYTES];

    const int ctx  = CTX[0];                 // 2048 (multiple of 64)
    const int tid  = (int)threadIdx.x;
    const int wave = tid >> 6;
    const int lane = tid & 63;
    const int low  = lane & 15;
    const int hi   = lane >> 4;

    // XCD mapping: the 8 q-tile blocks of one (b,kvh) share bid%8 -> same XCD L2
    const int bid   = (int)blockIdx.x;
    const int kvh   = bid & 7;
    const int b     = (bid >> 3) & 7;
    const int qtile = bid >> 6;
    const int head  = kvh * GRP + wave;
    const int q0    = qtile * 16;

    const int qtok = b * LQB + q0 + low;
    const float* qrow = Q + (size_t)qtok * (NH * HD) + head * HD;

    bf16x8 qf[4];                            // Q B-fragments, scale folded with log2e
    #pragma unroll
    for (int c = 0; c < 4; ++c) qf[c] = cvt8s(qrow + 32 * c + 8 * hi, QK_SCALE * LOG2E);

    f32x4 acc[8];
    #pragma unroll
    for (int c = 0; c < 8; ++c) acc[c] = (f32x4){0.f, 0.f, 0.f, 0.f};
    float mrun = -1e30f, lrun = 0.f;

    const int vis    = ctx + (((q0 >> 5) + 1) << 5);  // visible keys
    const int nsteps = (vis + 63) >> 6;               // last step may mask its top 32

    // staging ids: K: thread = (row, 32-float col chunk); V: thread = (key quad, 8-d group)
    const int skey = tid >> 2;               // 0..63
    const int scol = tid & 3;                // 0..3
    const int kxr  = (skey & 7) << 4;
    const int vkq  = tid & 15;               // keys 4*vkq..+3
    const int vdc2 = tid >> 4;               // d = 8*vdc2..+7

    f32x4 kr[8], vr[8];                      // in-flight staging registers

    auto issue_loads = [&](int t0) {
        {   // K: one row, 32 consecutive floats
            const int tok = t0 + skey;
            const float* src; size_t ro;
            if (tok < ctx) {
                const int pg = PT[b * PTSTRIDE + (tok >> 4)];
                src = Kc; ro = ((size_t)pg * 16 + (tok & 15)) * KVROW + kvh * HD;
            } else {
                src = Kn; ro = (size_t)(b * LQB + tok - ctx) * KVROW + kvh * HD;
            }
            const f32x4* p = reinterpret_cast<const f32x4*>(src + ro + 32 * scol);
            #pragma unroll
            for (int i = 0; i < 8; ++i) kr[i] = p[i];
        }
        {   // V: 4 consecutive key rows (4-aligned -> same page), 8 d each
            const int tok0 = t0 + 4 * vkq;
            const float* src; size_t ro;
            if (tok0 < ctx) {
                const int pg = PT[b * PTSTRIDE + (tok0 >> 4)];
                src = Vc; ro = ((size_t)pg * 16 + (tok0 & 15)) * KVROW + kvh * HD;
            } else {
                src = Vn; ro = (size_t)(b * LQB + tok0 - ctx) * KVROW + kvh * HD;
            }
            const float* base = src + ro + 8 * vdc2;
            #pragma unroll
            for (int r = 0; r < 4; ++r) {
                vr[2 * r]     = *reinterpret_cast<const f32x4*>(base + r * KVROW);
                vr[2 * r + 1] = *reinterpret_cast<const f32x4*>(base + r * KVROW + 4);
            }
        }
    };

    auto write_tile = [&](int buf) {
        // K: 4 swizzled 16B chunks
        unsigned char* ks = smem + KS_OFF(buf) + skey * 256;
        #pragma unroll
        for (int u = 0; u < 4; ++u) {
            bf16x8 w;
            #pragma unroll
            for (int j = 0; j < 4; ++j) {
                w[j]     = (__bf16)kr[2 * u][j];
                w[4 + j] = (__bf16)kr[2 * u + 1][j];
            }
            *reinterpret_cast<bf16x8*>(ks + ((64 * scol + 16 * u) ^ kxr)) = w;
        }
        // Vt: 8 x b64 (4 consecutive keys at one d)
        unsigned char* vt = smem + VT_OFF(buf) + 8 * vkq;
        #pragma unroll
        for (int di = 0; di < 8; ++di) {
            bf16x4 w;
            #pragma unroll
            for (int r = 0; r < 4; ++r) w[r] = (__bf16)vr[2 * r + (di >> 2)][di & 3];
            *reinterpret_cast<bf16x4*>(vt + (8 * vdc2 + di) * VT_STRIDE) = w;
        }
    };

    issue_loads(0);
    write_tile(0);
    __syncthreads();

    int cur = 0;
    for (int s = 0; s < nsteps; ++s) {
        const int t0 = s << 6;
        if (s + 1 < nsteps) issue_loads((s + 1) << 6);   // land during compute

        const unsigned char* ks = smem + KS_OFF(cur);
        const unsigned char* vt = smem + VT_OFF(cur);
        const int xr = (low & 7) << 4;

        // S^T: 4 chunks of 16 keys, 4 independent accumulator chains
        f32x4 sc[4];
        #pragma unroll
        for (int k = 0; k < 4; ++k) sc[k] = (f32x4){0.f, 0.f, 0.f, 0.f};
        #pragma unroll
        for (int c = 0; c < 4; ++c) {
            #pragma unroll
            for (int k = 0; k < 4; ++k) {
                bf16x8 kf = *reinterpret_cast<const bf16x8*>(
                    ks + (16 * k + low) * 256 + ((64 * c + 16 * hi) ^ xr));
                sc[k] = __builtin_amdgcn_mfma_f32_16x16x32_bf16(kf, qf[c], sc[k], 0, 0, 0);
            }
        }

        // tail: mask keys beyond visibility (scores are real tokens, just not visible)
        if (t0 + 32 >= vis) {
            #pragma unroll
            for (int j = 0; j < 4; ++j) { sc[2][j] = -1e30f; sc[3][j] = -1e30f; }
        }

        // local max over this lane's 16 scores
        float pmax = sc[0][0];
        #pragma unroll
        for (int k = 0; k < 4; ++k)
            #pragma unroll
            for (int j = 0; j < 4; ++j) pmax = fmaxf(pmax, sc[k][j]);

        // defer-max: full reduce + rescale only when the bound grows too much
        if (!__all(pmax - mrun <= DEFER_THR)) {
            float pm = fmaxf(pmax, __shfl_xor(pmax, 16));
            pm = fmaxf(pm, __shfl_xor(pm, 32));
            const float mnew = fmaxf(mrun, pm);
            const float corr = exp2f(mrun - mnew);
            mrun = mnew;
            lrun *= corr;
            #pragma unroll
            for (int c = 0; c < 8; ++c) acc[c] *= corr;
        }

        float p[16];
        float sum = 0.f;
        #pragma unroll
        for (int k = 0; k < 4; ++k)
            #pragma unroll
            for (int j = 0; j < 4; ++j) {
                p[4 * k + j] = exp2f(sc[k][j] - mrun);
                sum += p[4 * k + j];
            }
        lrun += sum;

        bf16x8 pf[2];                        // P^T B-fragments per 32-key half
        #pragma unroll
        for (int h = 0; h < 2; ++h)
            #pragma unroll
            for (int j = 0; j < 4; ++j) {
                pf[h][j]     = (__bf16)p[8 * h + j];
                pf[h][4 + j] = (__bf16)p[8 * h + 4 + j];
            }

        #pragma unroll
        for (int c = 0; c < 8; ++c) {
            const unsigned char* vrow = vt + (16 * c + low) * VT_STRIDE;
            #pragma unroll
            for (int h = 0; h < 2; ++h) {
                bf16x4 a0 = *reinterpret_cast<const bf16x4*>(vrow + 64 * h + 8 * hi);
                bf16x4 a1 = *reinterpret_cast<const bf16x4*>(vrow + 64 * h + 32 + 8 * hi);
                bf16x8 vf;
                vf[0] = a0[0]; vf[1] = a0[1]; vf[2] = a0[2]; vf[3] = a0[3];
                vf[4] = a1[0]; vf[5] = a1[1]; vf[6] = a1[2]; vf[7] = a1[3];
                acc[c] = __builtin_amdgcn_mfma_f32_16x16x32_bf16(vf, pf[h], acc[c], 0, 0, 0);
            }
        }

        if (s + 1 < nsteps) write_tile(cur ^ 1);   // regs -> LDS after compute
        __syncthreads();
        cur ^= 1;
    }

    lrun += __shfl_xor(lrun, 16);
    lrun += __shfl_xor(lrun, 32);
    const float inv = 1.0f / lrun;

    float* orow = O + (size_t)qtok * (NH * HD) + head * HD;
    #pragma unroll
    for (int c = 0; c < 8; ++c) {
        f32x4 r = acc[c] * inv;
        *reinterpret_cast<f32x4*>(orow + 16 * c + 4 * hi) = r;
    }
}

extern "C" void kernel_launch(void* const* d_in, const int* in_sizes, int n_in,
                              void* d_out, int out_size, void* d_ws, size_t ws_size,
                              hipStream_t stream) {
    const float* q  = (const float*)d_in[0];
    const float* k  = (const float*)d_in[1];
    const float* v  = (const float*)d_in[2];
    const float* kc = (const float*)d_in[3];
    const float* vc = (const float*)d_in[4];
    const int*   pt = (const int*)d_in[5];
    const int*   cx = (const int*)d_in[6];
    float* out = (float*)d_out;

    attn_fwd<<<dim3(512), dim3(256), 0, stream>>>(q, k, v, kc, vc, pt, cx, out);
}

// Round 4
// 271.479 us; speedup vs baseline: 1.0696x; 1.0696x over previous
//
#include <hip/hip_runtime.h>
#include <math.h>

#define NH 32
#define NKVH 8
#define GRP 4
#define HD 128
#define LQB 128
#define B_SEQ 8
#define PTSTRIDE 128
#define KVROW (NKVH * HD)          // 1024 floats per token row
#define QK_SCALE 0.08838834764831845f
#define LOG2E 1.4426950408889634f
#define DEFER_THR 8.0f
#define NROWS (B_SEQ * LQB * NH)   // 32768 (q-row, head) pairs

typedef __attribute__((ext_vector_type(8))) __bf16 bf16x8;
typedef __attribute__((ext_vector_type(4))) __bf16 bf16x4;
typedef __attribute__((ext_vector_type(4))) float f32x4;

// LDS per buffer: K: 32 keys x 128 d bf16, 256B rows, 16-slot XOR swizzle ((row&15)<<4)
//                 Vt: 128 d x 40 keys bf16 (pad -> 80B rows, reads 2-way free)
#define KS_BYTES 8192
#define VT_STRIDE 80
#define VT_BYTES 10240
#define KS_OFF(b) ((b) * KS_BYTES)
#define VT_OFF(b) (2 * KS_BYTES + (b) * VT_BYTES)
// total LDS = 36864 B -> 4 blocks/CU (144 KB of 160 KB)

static __device__ __forceinline__ bf16x8 cvt8s(const float* __restrict__ p, float s) {
    const f32x4 a = *reinterpret_cast<const f32x4*>(p);
    const f32x4 b = *reinterpret_cast<const f32x4*>(p + 4);
    bf16x8 r;
    r[0] = (__bf16)(a[0] * s); r[1] = (__bf16)(a[1] * s);
    r[2] = (__bf16)(a[2] * s); r[3] = (__bf16)(a[3] * s);
    r[4] = (__bf16)(b[0] * s); r[5] = (__bf16)(b[1] * s);
    r[6] = (__bf16)(b[2] * s); r[7] = (__bf16)(b[3] * s);
    return r;
}

// Wave = 16 q-rows of one head; block = 4 heads of one kv group (shared K/V in LDS).
// Swapped QK^T => softmax lane-local (+2 shfl only on rescale steps, deferred-max).
// SPLIT: flash-decoding 2-way over keys -> 1024 blocks, 4 blocks/CU, 16 waves/CU.
template<bool SPLIT>
__global__ __launch_bounds__(256, 4)
void attn_fwd(const float* __restrict__ Q,
              const float* __restrict__ Kn,
              const float* __restrict__ Vn,
              const float* __restrict__ Kc,
              const float* __restrict__ Vc,
              const int* __restrict__ PT,
              const int* __restrict__ CTX,
              float* __restrict__ O,
              float* __restrict__ WA,      // [2][NROWS][HD] unnormalized partial O
              float2* __restrict__ WML)    // [2][NROWS] (m, l) in log2 domain
{
    __shared__ __align__(16) unsigned char smem[2 * KS_BYTES + 2 * VT_BYTES];

    const int ctx  = CTX[0];                 // 2048 (multiple of 32)
    const int tid  = (int)threadIdx.x;
    const int wave = tid >> 6;
    const int lane = tid & 63;
    const int low  = lane & 15;
    const int hi   = lane >> 4;

    // XCD mapping: all blocks of one (b,kvh) share bid%8 -> same XCD L2
    const int bid   = (int)blockIdx.x;
    const int kvh   = bid & 7;
    const int b     = (bid >> 3) & 7;
    const int qtile = (bid >> 6) & 7;
    const int sk    = SPLIT ? (bid >> 9) : 0;
    const int head  = kvh * GRP + wave;
    const int q0    = qtile * 16;

    const int qtok = b * LQB + q0 + low;
    const float* qrow = Q + (size_t)qtok * (NH * HD) + head * HD;

    bf16x8 qf[4];                            // Q B-fragments, scale*log2e folded
    #pragma unroll
    for (int c = 0; c < 4; ++c) qf[c] = cvt8s(qrow + 32 * c + 8 * hi, QK_SCALE * LOG2E);

    f32x4 acc[8];
    #pragma unroll
    for (int c = 0; c < 8; ++c) acc[c] = (f32x4){0.f, 0.f, 0.f, 0.f};
    float mrun = -1e30f, lrun = 0.f;

    const int vis  = ctx + (((q0 >> 5) + 1) << 5);   // visible keys (mult of 32)
    const int c0   = (ctx >> 1) & ~31;               // split boundary
    const int kbeg = (SPLIT && sk) ? c0 : 0;
    const int kend = SPLIT ? (sk ? vis : c0) : vis;
    const int nsteps = (kend - kbeg) >> 5;

    // staging ids
    const int skey = tid >> 3;               // K: key row 0..31
    const int sc8  = tid & 7;                // K: 16-float col chunk
    const int kxr  = (skey & 15) << 4;       // full 16-slot swizzle
    const int vdc  = tid >> 3;               // V: d-chunk (4 floats) 0..31
    const int vkq  = tid & 7;                // V: key quad 0..7

    f32x4 kr[4], vr[4];                      // in-flight staging registers

    auto issue_loads = [&](int t0) {
        {   // K row skey, 16 floats at 16*sc8
            const int tok = t0 + skey;
            const float* src; size_t ro;
            if (tok < ctx) {
                const int pg = PT[b * PTSTRIDE + (tok >> 4)];
                src = Kc; ro = ((size_t)pg * 16 + (tok & 15)) * KVROW + kvh * HD;
            } else {
                src = Kn; ro = (size_t)(b * LQB + tok - ctx) * KVROW + kvh * HD;
            }
            const f32x4* p = reinterpret_cast<const f32x4*>(src + ro + 16 * sc8);
            kr[0] = p[0]; kr[1] = p[1]; kr[2] = p[2]; kr[3] = p[3];
        }
        {   // V: 4 consecutive key rows (4-aligned -> same page), 4 d each
            const int tok0 = t0 + 4 * vkq;
            const float* src; size_t ro;
            if (tok0 < ctx) {
                const int pg = PT[b * PTSTRIDE + (tok0 >> 4)];
                src = Vc; ro = ((size_t)pg * 16 + (tok0 & 15)) * KVROW + kvh * HD;
            } else {
                src = Vn; ro = (size_t)(b * LQB + tok0 - ctx) * KVROW + kvh * HD;
            }
            const float* base = src + ro + 4 * vdc;
            vr[0] = *reinterpret_cast<const f32x4*>(base);
            vr[1] = *reinterpret_cast<const f32x4*>(base + KVROW);
            vr[2] = *reinterpret_cast<const f32x4*>(base + 2 * KVROW);
            vr[3] = *reinterpret_cast<const f32x4*>(base + 3 * KVROW);
        }
    };

    auto write_tile = [&](int buf) {
        unsigned char* ks = smem + KS_OFF(buf) + skey * 256;
        bf16x8 c0w, c1w;
        #pragma unroll
        for (int j = 0; j < 4; ++j) {
            c0w[j] = (__bf16)kr[0][j]; c0w[j + 4] = (__bf16)kr[1][j];
            c1w[j] = (__bf16)kr[2][j]; c1w[j + 4] = (__bf16)kr[3][j];
        }
        *reinterpret_cast<bf16x8*>(ks + ((32 * sc8) ^ kxr))      = c0w;
        *reinterpret_cast<bf16x8*>(ks + ((32 * sc8 + 16) ^ kxr)) = c1w;
        unsigned char* vt = smem + VT_OFF(buf) + 8 * vkq;
        #pragma unroll
        for (int di = 0; di < 4; ++di) {
            bf16x4 w;
            w[0] = (__bf16)vr[0][di]; w[1] = (__bf16)vr[1][di];
            w[2] = (__bf16)vr[2][di]; w[3] = (__bf16)vr[3][di];
            *reinterpret_cast<bf16x4*>(vt + (4 * vdc + di) * VT_STRIDE) = w;
        }
    };

    if (nsteps > 0) {
        issue_loads(kbeg);
        write_tile(0);
        __syncthreads();

        int cur = 0;
        for (int s = 0; s < nsteps; ++s) {
            if (s + 1 < nsteps) issue_loads(kbeg + ((s + 1) << 5));

            const unsigned char* ks = smem + KS_OFF(cur);
            const unsigned char* vt = smem + VT_OFF(cur);
            const int xr = low << 4;

            f32x4 s0 = (f32x4){0.f, 0.f, 0.f, 0.f};
            f32x4 s1 = (f32x4){0.f, 0.f, 0.f, 0.f};
            #pragma unroll
            for (int c = 0; c < 4; ++c) {
                bf16x8 ka = *reinterpret_cast<const bf16x8*>(ks + low * 256 + ((64 * c + 16 * hi) ^ xr));
                bf16x8 kb = *reinterpret_cast<const bf16x8*>(ks + (16 + low) * 256 + ((64 * c + 16 * hi) ^ xr));
                s0 = __builtin_amdgcn_mfma_f32_16x16x32_bf16(ka, qf[c], s0, 0, 0, 0);
                s1 = __builtin_amdgcn_mfma_f32_16x16x32_bf16(kb, qf[c], s1, 0, 0, 0);
            }

            float pmax = fmaxf(fmaxf(fmaxf(s0[0], s0[1]), fmaxf(s0[2], s0[3])),
                               fmaxf(fmaxf(s1[0], s1[1]), fmaxf(s1[2], s1[3])));

            // defer-max: cross-lane reduce + rescale only when bound grows
            if (!__all(pmax - mrun <= DEFER_THR)) {
                float pm = fmaxf(pmax, __shfl_xor(pmax, 16));
                pm = fmaxf(pm, __shfl_xor(pm, 32));
                const float mnew = fmaxf(mrun, pm);
                const float corr = exp2f(mrun - mnew);
                mrun = mnew;
                lrun *= corr;
                #pragma unroll
                for (int c = 0; c < 8; ++c) acc[c] *= corr;
            }

            float p[8];
            #pragma unroll
            for (int j = 0; j < 4; ++j) {
                p[j]     = exp2f(s0[j] - mrun);
                p[j + 4] = exp2f(s1[j] - mrun);
            }
            lrun += (((p[0] + p[1]) + (p[2] + p[3])) + ((p[4] + p[5]) + (p[6] + p[7])));

            bf16x8 pf;
            #pragma unroll
            for (int j = 0; j < 8; ++j) pf[j] = (__bf16)p[j];

            #pragma unroll
            for (int c = 0; c < 8; ++c) {
                const unsigned char* vrow = vt + (16 * c + low) * VT_STRIDE + 8 * hi;
                bf16x4 a0 = *reinterpret_cast<const bf16x4*>(vrow);
                bf16x4 a1 = *reinterpret_cast<const bf16x4*>(vrow + 32);
                bf16x8 vf;
                vf[0] = a0[0]; vf[1] = a0[1]; vf[2] = a0[2]; vf[3] = a0[3];
                vf[4] = a1[0]; vf[5] = a1[1]; vf[6] = a1[2]; vf[7] = a1[3];
                acc[c] = __builtin_amdgcn_mfma_f32_16x16x32_bf16(vf, pf, acc[c], 0, 0, 0);
            }

            if (s + 1 < nsteps) write_tile(cur ^ 1);
            __syncthreads();
            cur ^= 1;
        }
    }

    lrun += __shfl_xor(lrun, 16);
    lrun += __shfl_xor(lrun, 32);

    const int r = qtok * NH + head;          // (q-row, head) index, 0..NROWS
    if (SPLIT) {
        float* oa = WA + ((size_t)sk * NROWS + r) * HD;
        #pragma unroll
        for (int c = 0; c < 8; ++c)
            *reinterpret_cast<f32x4*>(oa + 16 * c + 4 * hi) = acc[c];
        if (hi == 0) WML[sk * NROWS + r] = make_float2(mrun, lrun);
    } else {
        const float inv = 1.0f / lrun;
        float* orow = O + (size_t)r * HD;
        #pragma unroll
        for (int c = 0; c < 8; ++c) {
            f32x4 v = acc[c] * inv;
            *reinterpret_cast<f32x4*>(orow + 16 * c + 4 * hi) = v;
        }
    }
}

// combine the two split-K partials: out = sum_i acc_i * 2^(m_i - M) / sum_i l_i * 2^(m_i - M)
__global__ __launch_bounds__(256)
void combine(const float* __restrict__ WA, const float2* __restrict__ WML,
             float* __restrict__ O)
{
    const int idx = (int)blockIdx.x * 256 + (int)threadIdx.x;  // NROWS*32 works
    const int r  = idx >> 5;
    const int dq = idx & 31;
    const float2 ml0 = WML[r];
    const float2 ml1 = WML[NROWS + r];
    const float M  = fmaxf(ml0.x, ml1.x);
    const float e0 = exp2f(ml0.x - M);
    const float e1 = exp2f(ml1.x - M);
    const float inv = 1.0f / (ml0.y * e0 + ml1.y * e1);
    const f32x4 a0 = *reinterpret_cast<const f32x4*>(WA + (size_t)r * HD + 4 * dq);
    const f32x4 a1 = *reinterpret_cast<const f32x4*>(WA + ((size_t)NROWS + r) * HD + 4 * dq);
    f32x4 o = (a0 * e0 + a1 * e1) * inv;
    *reinterpret_cast<f32x4*>(O + (size_t)r * HD + 4 * dq) = o;
}

extern "C" void kernel_launch(void* const* d_in, const int* in_sizes, int n_in,
                              void* d_out, int out_size, void* d_ws, size_t ws_size,
                              hipStream_t stream) {
    const float* q  = (const float*)d_in[0];
    const float* k  = (const float*)d_in[1];
    const float* v  = (const float*)d_in[2];
    const float* kc = (const float*)d_in[3];
    const float* vc = (const float*)d_in[4];
    const int*   pt = (const int*)d_in[5];
    const int*   cx = (const int*)d_in[6];
    float* out = (float*)d_out;

    const size_t wa_bytes = (size_t)2 * NROWS * HD * sizeof(float);
    const size_t needed   = wa_bytes + (size_t)2 * NROWS * sizeof(float2);

    if (ws_size >= needed) {
        float*  wa  = (float*)d_ws;
        float2* wml = (float2*)((char*)d_ws + wa_bytes);
        attn_fwd<true><<<dim3(1024), dim3(256), 0, stream>>>(q, k, v, kc, vc, pt, cx, out, wa, wml);
        combine<<<dim3(NROWS * 32 / 256), dim3(256), 0, stream>>>(wa, wml, out);
    } else {
        attn_fwd<false><<<dim3(512), dim3(256), 0, stream>>>(q, k, v, kc, vc, pt, cx, out,
                                                             nullptr, nullptr);
    }
}